// Round 12
// baseline (466.513 us; speedup 1.0000x reference)
//
#include <hip/hip_runtime.h>
#include <hip/hip_bf16.h>

// ---- problem constants ----
#define B_    1024
#define D_    384
#define Q_    65536
#define N_    66560            // B_ + Q_
#define TOPK_ 128

#define NBIN_ 4096             // histogram bins = key >> 4
#define CAP_  2048             // boundary-bin candidate cap

typedef __bf16 bf16x8 __attribute__((ext_vector_type(8)));
typedef float  f32x4  __attribute__((ext_vector_type(4)));
typedef unsigned short u16;
typedef u16 u16x8 __attribute__((ext_vector_type(8)));

// RNE float -> bf16 (bit-level)
__device__ __forceinline__ unsigned short f2bf(float x) {
  unsigned int u = __float_as_uint(x);
  unsigned int r = (u + 0x7fffu + ((u >> 16) & 1u)) >> 16;
  return (unsigned short)r;
}

__device__ __forceinline__ void gld_lds16(const void* g, void* l) {
  __builtin_amdgcn_global_load_lds(
      (__attribute__((address_space(1))) void*)(g),
      (__attribute__((address_space(3))) void*)(l), 16, 0, 0);
}

__device__ __forceinline__ void wait_vmcnt(int n) {
  if (n == 6) asm volatile("s_waitcnt vmcnt(6)" ::: "memory");
  else        asm volatile("s_waitcnt vmcnt(0)" ::: "memory");
}

// monotone key from bf16 bits
__device__ __forceinline__ unsigned int bf2key(unsigned int u) {
  return u ^ ((u & 0x8000u) ? 0xFFFFu : 0x8000u);
}

// ---------------------------------------------------------------------------
// Normalize rgb/ir feats -> bf16 z (Ball role) and bf16 z/temp (A role).
// ---------------------------------------------------------------------------
__global__ __launch_bounds__(64) void k_normalize(
    const float* __restrict__ rgb, const float* __restrict__ ir,
    const int* __restrict__ ep,
    u16* __restrict__ zrA, u16* __restrict__ ziA,
    u16* __restrict__ zrU, u16* __restrict__ ziU)
{
  int r = blockIdx.x & (B_ - 1);
  bool isIr = blockIdx.x >= B_;
  const float* src = (isIr ? ir : rgb) + (size_t)r * D_;
  u16* dA = (isIr ? ziA : zrA) + (size_t)r * D_;
  u16* dU = (isIr ? ziU : zrU) + (size_t)r * D_;
  int t = threadIdx.x;
  float x[6]; float ss = 0.f;
  #pragma unroll
  for (int k = 0; k < 6; ++k) { x[k] = src[t + 64*k]; ss += x[k]*x[k]; }
  #pragma unroll
  for (int off = 32; off > 0; off >>= 1) ss += __shfl_down(ss, off);
  ss = __shfl(ss, 0);
  float inv = 1.0f / fmaxf(sqrtf(ss), 1e-12f);

  int e = ep[0];
  float temp;
  if (e >= 10) temp = 0.05f;
  else {
    float p = (float)e * 0.1f;
    temp = 0.05f + 0.075f * (1.0f + cosf(3.14159265358979323846f * p));
  }
  float itemp = 1.0f / temp;

  #pragma unroll
  for (int k = 0; k < 6; ++k) {
    float z = x[k] * inv;
    dU[t + 64*k] = f2bf(z);
    dA[t + 64*k] = f2bf(z * itemp);
  }
}

// ---------------------------------------------------------------------------
// GEMM body: 128(M)x256(N) tile, 4 waves, per-wave 128x64 (acc 8x4).
// BK=32, 12 steps, 2 x 24KB LDS buffers (48KB -> 3 blocks/CU), counted
// vmcnt(6) pipeline (stage t+2 issued at iter end, never drain mid-loop).
// T1 bijective XCD swizzle (uses nwg param, NOT gridDim), T2 XOR swizzle.
// Epilogue: diag extract+poison, 2-pass 64-row LDS bounce, 16B stores.
// ---------------------------------------------------------------------------
__device__ __forceinline__ void gemm_body(
    unsigned char* smem, int bid,
    const u16* __restrict__ A, const u16* __restrict__ ball,
    u16* __restrict__ C, float* __restrict__ diag,
    int r0, int mtiles, int nwg)
{
  int xcd = bid & 7, loc = bid >> 3;
  int q = nwg >> 3, r8 = nwg & 7;
  int wgid = (xcd < r8 ? xcd * (q + 1) : r8 * (q + 1) + (xcd - r8) * q) + loc;
  int nt = wgid / mtiles;
  int mt = wgid - nt * mtiles;

  const int tid  = threadIdx.x;
  const int wave = tid >> 6, lane = tid & 63;
  const int mbase = mt * 128;
  const int nbase = nt * 256;
  const u16* Ab = A    + (size_t)(r0 + mbase) * D_;
  const u16* Bb = ball + (size_t)nbase * D_;

  u16* Ct = (u16*)smem;            // epilogue bounce [64][264] per pass

  auto As = [&](int t) -> u16* { return (u16*)(smem + (t & 1) * 24576); };
  auto Bs = [&](int t) -> u16* { return (u16*)(smem + (t & 1) * 24576 + 8192); };
  auto stage = [&](int t) {
    const int ks = t * 32;
    #pragma unroll
    for (int i = 0; i < 2; ++i) {
      int f = i * 256 + tid, rr = f >> 2, cc = f & 3;
      int koff = (((cc * 16) ^ (((rr >> 1) & 3) << 4)) >> 1);
      gld_lds16(Ab + (size_t)rr * D_ + ks + koff, As(t) + (size_t)f * 8);
    }
    #pragma unroll
    for (int i = 0; i < 4; ++i) {
      int f = i * 256 + tid, rr = f >> 2, cc = f & 3;
      int koff = (((cc * 16) ^ (((rr >> 1) & 3) << 4)) >> 1);
      gld_lds16(Bb + (size_t)rr * D_ + ks + koff, Bs(t) + (size_t)f * 8);
    }
  };

  f32x4 acc[8][4];
  #pragma unroll
  for (int m = 0; m < 8; ++m)
    #pragma unroll
    for (int n = 0; n < 4; ++n)
      #pragma unroll
      for (int r = 0; r < 4; ++r) acc[m][n][r] = 0.0f;

  const int lr = lane & 15;
  const int kb = (lane >> 4) * 16;   // byte column within the 64B row

  stage(0); stage(1);                // 12 loads in flight

  #pragma unroll
  for (int t = 0; t < 12; ++t) {
    wait_vmcnt(t < 11 ? 6 : 0);      // tile t landed; t+1 stays in flight
    __builtin_amdgcn_s_barrier();    // tile t visible to all waves
    __builtin_amdgcn_sched_barrier(0);

    const u16* Ac = As(t);
    const u16* Bc = Bs(t);
    bf16x8 af[8], bq[4];
    #pragma unroll
    for (int m = 0; m < 8; ++m) {
      int row = m*16 + lr;           // all waves read all 128 A rows
      af[m] = *(const bf16x8*)((const char*)Ac + row * 64 + (kb ^ (((row >> 1) & 3) << 4)));
    }
    #pragma unroll
    for (int n = 0; n < 4; ++n) {
      int row = wave*64 + n*16 + lr; // wave's private 64-col B stripe
      bq[n] = *(const bf16x8*)((const char*)Bc + row * 64 + (kb ^ (((row >> 1) & 3) << 4)));
    }
    #pragma unroll
    for (int m = 0; m < 8; ++m)
      #pragma unroll
      for (int n = 0; n < 4; ++n)
        acc[m][n] = __builtin_amdgcn_mfma_f32_16x16x32_bf16(af[m], bq[n], acc[m][n], 0, 0, 0);

    asm volatile("s_waitcnt lgkmcnt(0)" ::: "memory");
    __builtin_amdgcn_sched_barrier(0);
    __builtin_amdgcn_s_barrier();    // all reads of buffer t&1 done
    if (t + 2 < 12) stage(t + 2);    // overwrite buffer t&1 with tile t+2
  }

  // ---- epilogue: 2 passes of 64 rows via LDS bounce [64][264] ----
  const int rowq = (lane >> 4) * 4;
  #pragma unroll
  for (int pass = 0; pass < 2; ++pass) {
    if (pass) __syncthreads();
    #pragma unroll
    for (int mm = 0; mm < 4; ++mm) {
      int m = pass * 4 + mm;
      #pragma unroll
      for (int n = 0; n < 4; ++n) {
        int lcol = wave*64 + n*16 + lr;
        int gcol = nbase + lcol;
        #pragma unroll
        for (int r = 0; r < 4; ++r) {
          int lrow = m*16 + rowq + r;          // 0..127
          float x = acc[m][n][r];
          int grow = r0 + mbase + lrow;
          if (gcol == grow) { diag[grow] = x; x = -60.0f; }
          Ct[(lrow - pass*64) * 264 + lcol] = f2bf(x);
        }
      }
    }
    __syncthreads();
    #pragma unroll
    for (int j = 0; j < 8; ++j) {
      int id = j * 256 + tid;                  // 0..2047
      int row = id >> 5, cc8 = (id & 31) * 8;
      u16x8 v = *(const u16x8*)(Ct + row * 264 + cc8);
      *(u16x8*)(C + (size_t)(mbase + pass*64 + row) * N_ + nbase + cc8) = v;
    }
  }
}

// ---------------------------------------------------------------------------
// Select body: per-row exact top-128 + expsum + loss (2-sweep radix select).
// LDS carved from shared smem: hist 16K | vals 8K | fred 1K | csum 1K | 3 ints.
// ---------------------------------------------------------------------------
__device__ __forceinline__ void select_body(
    unsigned char* smem, int sbid,
    const u16* __restrict__ C, const float* __restrict__ diag,
    float* __restrict__ rowloss, int r0)
{
  unsigned int* hist = (unsigned int*)smem;             // 16384 B
  float*        vals = (float*)(smem + 16384);          // 8192 B
  float*        fred = (float*)(smem + 24576);          // 1024 B
  unsigned int* csum = (unsigned int*)(smem + 25600);   // 1024 B
  int*          shv  = (int*)(smem + 26624);            // [0]=bstar [1]=above [2]=cnt

  const int t = threadIdx.x;
  const int grow = r0 + sbid;
  const u16x8* p = (const u16x8*)(C + (size_t)sbid * N_);

  uint4* h4 = (uint4*)hist;
  #pragma unroll
  for (int i = 0; i < 4; ++i) h4[i * 256 + t] = make_uint4(0,0,0,0);
  if (t == 0) shv[2] = 0;
  __syncthreads();

  // ---- sweep 1: expsum + histogram ----
  float es0 = 0.f, es1 = 0.f;
  #pragma unroll 1
  for (int base = 0; base < 8192; base += 2048) {
    u16x8 v[8];
    #pragma unroll
    for (int j = 0; j < 8; ++j) v[j] = p[base + j * 256 + t];
    #pragma unroll
    for (int j = 0; j < 8; ++j) {
      #pragma unroll
      for (int e = 0; e < 8; ++e) {
        unsigned int u = (unsigned int)(unsigned short)v[j][e];
        atomicAdd(&hist[bf2key(u) >> 4], 1u);
        float ex = __expf(__uint_as_float(u << 16));
        if (j & 1) es1 += ex; else es0 += ex;
      }
    }
  }
  if (t < 128) {                         // tail: chunks 8192..8319
    u16x8 v = p[8192 + t];
    #pragma unroll
    for (int e = 0; e < 8; ++e) {
      unsigned int u = (unsigned int)(unsigned short)v[e];
      atomicAdd(&hist[bf2key(u) >> 4], 1u);
      es0 += __expf(__uint_as_float(u << 16));
    }
  }
  float esum = es0 + es1;
  __syncthreads();

  // ---- chunk sums: thread t owns bins [16t, 16t+16) ----
  unsigned int S = 0;
  #pragma unroll
  for (int i = 0; i < 16; ++i) S += hist[t * 16 + i];
  csum[t] = S;
  __syncthreads();

  // ---- suffix-inclusive scan ----
  unsigned int a = S;
  #pragma unroll
  for (int s = 1; s < 256; s <<= 1) {
    unsigned int add = (t + s < 256) ? csum[t + s] : 0u;
    __syncthreads();
    a += add; csum[t] = a;
    __syncthreads();
  }

  // ---- locate exact boundary bin ----
  int above_chunk = (t < 255) ? (int)csum[t + 1] : 0;
  if (above_chunk < TOPK_ && above_chunk + (int)S >= TOPK_) {
    int cum = above_chunk;
    #pragma unroll 1
    for (int i = 15; i >= 0; --i) {
      int c = (int)hist[t * 16 + i];
      if (cum + c >= TOPK_) { shv[0] = t * 16 + i; shv[1] = cum; break; }
      cum += c;
    }
  }
  __syncthreads();
  const unsigned int bstar = (unsigned int)shv[0];
  const int A = shv[1];

  // ---- sweep 2: above-b* direct, boundary bin collected ----
  float delta = 0.f;
  #pragma unroll 1
  for (int base = 0; base < 8192; base += 2048) {
    u16x8 v[8];
    #pragma unroll
    for (int j = 0; j < 8; ++j) v[j] = p[base + j * 256 + t];
    #pragma unroll
    for (int j = 0; j < 8; ++j) {
      #pragma unroll
      for (int e = 0; e < 8; ++e) {
        unsigned int u = (unsigned int)(unsigned short)v[j][e];
        unsigned int bin = bf2key(u) >> 4;
        if (bin >= bstar) {
          float val = __uint_as_float(u << 16);
          if (bin > bstar) delta += __expf(2.f * val) - __expf(val);
          else { int s = atomicAdd(&shv[2], 1); if (s < CAP_) vals[s] = val; }
        }
      }
    }
  }
  if (t < 128) {
    u16x8 v = p[8192 + t];
    #pragma unroll
    for (int e = 0; e < 8; ++e) {
      unsigned int u = (unsigned int)(unsigned short)v[e];
      unsigned int bin = bf2key(u) >> 4;
      if (bin >= bstar) {
        float val = __uint_as_float(u << 16);
        if (bin > bstar) delta += __expf(2.f * val) - __expf(val);
        else { int s = atomicAdd(&shv[2], 1); if (s < CAP_) vals[s] = val; }
      }
    }
  }
  __syncthreads();

  // ---- exact rank within boundary bin ----
  int C2 = shv[2] < CAP_ ? shv[2] : CAP_;
  int need = TOPK_ - A;
  for (int i = t; i < C2; i += 256) {
    float v = vals[i];
    int g = 0;
    for (int k = 0; k < C2; ++k)
      g += (vals[k] > v) || (vals[k] == v && k < i);
    if (g < need) delta += __expf(2.f * v) - __expf(v);
  }

  fred[t] = esum + delta;
  __syncthreads();
  #pragma unroll
  for (int s = 128; s > 0; s >>= 1) { if (t < s) fred[t] += fred[t + s]; __syncthreads(); }

  if (t == 0) {
    float d = diag[grow];
    rowloss[grow] = logf(fred[0] + __expf(d)) - d;
  }
}

// ---------------------------------------------------------------------------
// Ball body: Ball bf16 [N_][D_] = [z_other bf16 ; queue f32->bf16]
// ---------------------------------------------------------------------------
__device__ __forceinline__ void ball_body(
    int bbid, const u16* __restrict__ zU, const float* __restrict__ queue,
    u16* __restrict__ ball)
{
  size_t i = ((size_t)bbid * 256 + threadIdx.x) * 8;
  const size_t zElems = (size_t)B_ * D_;
  if (i < zElems) {
    *(uint4*)(ball + i) = *(const uint4*)(zU + i);
  } else {
    const float* q = queue + (i - zElems);
    float4 a = *(const float4*)q;
    float4 b = *(const float4*)(q + 4);
    u16x8 o;
    o[0] = f2bf(a.x); o[1] = f2bf(a.y); o[2] = f2bf(a.z); o[3] = f2bf(a.w);
    o[4] = f2bf(b.x); o[5] = f2bf(b.y); o[6] = f2bf(b.z); o[7] = f2bf(b.w);
    *(u16x8*)(ball + i) = o;
  }
}

// ---------------------------------------------------------------------------
// Fused dispatcher: blocks [0,g_nwg) gemm | [g_nwg, +s_nblk) select |
// then b_nblk ball blocks. Independent jobs overlap within one launch.
// ---------------------------------------------------------------------------
__global__ __launch_bounds__(256, 3) void k_fused(
    const u16* gA, const u16* gBall, u16* gC, float* gDiag,
    int g_r0, int g_mtiles, int g_nwg,
    const u16* sC, const float* sDiag, float* sRow, int s_r0, int s_nblk,
    const u16* bZ, const float* bQ, u16* bBall, int b_nblk)
{
  __shared__ __align__(16) unsigned char smem[49152];
  int bid = blockIdx.x;
  if (bid < g_nwg) {
    gemm_body(smem, bid, gA, gBall, gC, gDiag, g_r0, g_mtiles, g_nwg);
    return;
  }
  bid -= g_nwg;
  if (bid < s_nblk) {
    select_body(smem, bid, sC, sDiag, sRow, s_r0);
    return;
  }
  bid -= s_nblk;
  if (bid < b_nblk) ball_body(bid, bZ, bQ, bBall);
}

__global__ __launch_bounds__(256) void k_final(
    const float* __restrict__ rowloss, float* __restrict__ out)
{
  __shared__ float red[256];
  int t = threadIdx.x;
  float s = 0.f;
  for (int i = t; i < 2 * B_; i += 256) s += rowloss[i];
  red[t] = s;
  __syncthreads();
  for (int k = 128; k > 0; k >>= 1) { if (t < k) red[t] += red[t + k]; __syncthreads(); }
  if (t == 0) out[0] = red[0] * (1.0f / (2.0f * B_));
}

// ---------------------------------------------------------------------------
extern "C" void kernel_launch(void* const* d_in, const int* in_sizes, int n_in,
                              void* d_out, int out_size, void* d_ws, size_t ws_size,
                              hipStream_t stream)
{
  const float* rgb_feat = (const float*)d_in[0];
  const float* ir_feat  = (const float*)d_in[1];
  const float* rgb_q    = (const float*)d_in[2];
  const float* ir_q     = (const float*)d_in[3];
  const int*   epoch    = (const int*)d_in[4];

  char* ws = (char*)d_ws;
  size_t off = 0;
  auto alloc = [&](size_t bytes) -> char* {
    char* p = ws + off;
    off = (off + bytes + 255) & ~(size_t)255;
    return p;
  };

  u16* zrA = (u16*)alloc((size_t)B_ * D_ * 2);
  u16* ziA = (u16*)alloc((size_t)B_ * D_ * 2);
  u16* zrU = (u16*)alloc((size_t)B_ * D_ * 2);
  u16* ziU = (u16*)alloc((size_t)B_ * D_ * 2);
  float* diag    = (float*)alloc((size_t)2 * B_ * 4);
  float* rowloss = (float*)alloc((size_t)2 * B_ * 4);
  u16* ball = (u16*)alloc((size_t)N_ * D_ * 2);

  size_t avail = ws_size > off ? ws_size - off : 0;
  const size_t halfBytes = (size_t)512 * N_ * 2;
  const int NBALL = (int)(((size_t)N_ * D_ / 8) / 256);  // 12480
  const u16* Z16 = nullptr; const float* F32 = nullptr;  // null shorthands

  k_normalize<<<dim3(2 * B_), dim3(64), 0, stream>>>(
      rgb_feat, ir_feat, epoch, zrA, ziA, zrU, ziU);

  if (avail >= 2 * halfBytes) {
    // ---- pipelined path: two 512-row half-slabs, fused overlap launches ----
    u16* slabA = (u16*)(ws + off);
    u16* slabB = slabA + (size_t)512 * N_;
    float* dg0 = diag;        float* dg1 = diag + B_;
    float* ls0 = rowloss;     float* ls1 = rowloss + B_;

    // ball0 (dir0 B-matrix: [ir_z ; ir_queue])
    k_fused<<<dim3(NBALL), dim3(256), 0, stream>>>(
        Z16, Z16, nullptr, nullptr, 0, 1, 0,
        Z16, F32, nullptr, 0, 0,
        ziU, ir_q, ball, NBALL);
    // gemm0a -> slabA
    k_fused<<<dim3(1040), dim3(256), 0, stream>>>(
        zrA, ball, slabA, dg0, 0, 4, 1040,
        Z16, F32, nullptr, 0, 0,
        Z16, F32, nullptr, 0);
    // gemm0b -> slabB  ||  select0a <- slabA
    k_fused<<<dim3(1040 + 512), dim3(256), 0, stream>>>(
        zrA, ball, slabB, dg0, 512, 4, 1040,
        slabA, dg0, ls0, 0, 512,
        Z16, F32, nullptr, 0);
    // select0b <- slabB  ||  ball1 (dir1 B-matrix: [rgb_z ; rgb_queue])
    k_fused<<<dim3(512 + NBALL), dim3(256), 0, stream>>>(
        Z16, Z16, nullptr, nullptr, 0, 1, 0,
        slabB, dg0, ls0, 512, 512,
        zrU, rgb_q, ball, NBALL);
    // gemm1a -> slabA
    k_fused<<<dim3(1040), dim3(256), 0, stream>>>(
        ziA, ball, slabA, dg1, 0, 4, 1040,
        Z16, F32, nullptr, 0, 0,
        Z16, F32, nullptr, 0);
    // gemm1b -> slabB  ||  select1a <- slabA
    k_fused<<<dim3(1040 + 512), dim3(256), 0, stream>>>(
        ziA, ball, slabB, dg1, 512, 4, 1040,
        slabA, dg1, ls1, 0, 512,
        Z16, F32, nullptr, 0);
    // select1b <- slabB
    k_fused<<<dim3(512), dim3(256), 0, stream>>>(
        Z16, Z16, nullptr, nullptr, 0, 1, 0,
        slabB, dg1, ls1, 512, 512,
        Z16, F32, nullptr, 0);
  } else {
    // ---- fallback: sequential, slab sized to what fits ----
    int SR = (int)(avail / ((size_t)N_ * 2));
    SR &= ~127;
    if (SR > B_) SR = B_;
    if (SR < 128) SR = 128;
    u16* slab = (u16*)(ws + off);

    for (int dir = 0; dir < 2; ++dir) {
      const u16*   Amat   = (dir == 0) ? zrA : ziA;
      const u16*   zOther = (dir == 0) ? ziU : zrU;
      const float* queue  = (dir == 0) ? ir_q : rgb_q;
      float* dg = diag    + dir * B_;
      float* ls = rowloss + dir * B_;

      k_fused<<<dim3(NBALL), dim3(256), 0, stream>>>(
          Z16, Z16, nullptr, nullptr, 0, 1, 0,
          Z16, F32, nullptr, 0, 0,
          zOther, queue, ball, NBALL);

      for (int r0 = 0; r0 < B_; r0 += SR) {
        int cur = (B_ - r0) < SR ? (B_ - r0) : SR;
        int mtiles = cur / 128;
        int nwg = (N_ / 256) * mtiles;
        k_fused<<<dim3(nwg), dim3(256), 0, stream>>>(
            Amat, ball, slab, dg, r0, mtiles, nwg,
            Z16, F32, nullptr, 0, 0,
            Z16, F32, nullptr, 0);
        k_fused<<<dim3(cur), dim3(256), 0, stream>>>(
            Z16, Z16, nullptr, nullptr, 0, 1, 0,
            slab, dg, ls, r0, cur,
            Z16, F32, nullptr, 0);
      }
    }
  }

  k_final<<<dim3(1), dim3(256), 0, stream>>>(rowloss, (float*)d_out);
}